// Round 1
// baseline (885.078 us; speedup 1.0000x reference)
//
#include <hip/hip_runtime.h>
#include <math.h>

// ---------------------------------------------------------------------------
// GATConv forward, f32.  N=100000 nodes, E=1.6M edges, IN=128, OUT*HEADS=128.
// Pipeline:
//   1) gemm_z    : Z[n, c] = sum_k x[n,k] * W[c,k] + b[c]       (c = o*4 + h)
//   2) node_e    : el[n,h] = sum_o Z[n,o*4+h]*a_l[o,h];  er likewise
//   3) edge_ex   : ex[e,h] = exp(leakyrelu(el[row]+er[col])); denom += ex
//                  (segment softmax WITHOUT max-subtraction: shift-invariant,
//                   |e| small -> no overflow; mathematically identical)
//   4) inv_den   : denom -> 1/denom
//   5) scatter   : out[row, c] += ex[e,h]*invden[row,h] * Z[col, c]  (atomic)
// ---------------------------------------------------------------------------

__global__ __launch_bounds__(256) void gemm_z(
    const float* __restrict__ x, const float* __restrict__ W,
    const float* __restrict__ bias, float* __restrict__ Z, int N) {
  // k-major staging; stride 132 keeps 16B alignment for b128 LDS reads.
  __shared__ float xs[128][132];
  __shared__ float ws[128][132];
  const int t = threadIdx.x;
  const int base = blockIdx.x * 128;

  // stage W: ws[k][c] = W[c][k]
#pragma unroll
  for (int i = 0; i < 16; ++i) {
    int f4 = i * 256 + t;
    int c = f4 >> 5;             // output channel (W row)
    int k = (f4 & 31) << 2;      // k start
    float4 v = reinterpret_cast<const float4*>(W)[f4];
    ws[k + 0][c] = v.x; ws[k + 1][c] = v.y;
    ws[k + 2][c] = v.z; ws[k + 3][c] = v.w;
  }
  // stage x: xs[k][r] = x[base+r][k]
#pragma unroll
  for (int i = 0; i < 16; ++i) {
    int f4 = i * 256 + t;
    int r = f4 >> 5;
    int k = (f4 & 31) << 2;
    int gr = base + r;
    float4 v = make_float4(0.f, 0.f, 0.f, 0.f);
    if (gr < N) v = reinterpret_cast<const float4*>(x)[(size_t)gr * 32 + (f4 & 31)];
    xs[k + 0][r] = v.x; xs[k + 1][r] = v.y;
    xs[k + 2][r] = v.z; xs[k + 3][r] = v.w;
  }
  __syncthreads();

  const int tx = t & 15, ty = t >> 4;
  const int c0 = tx * 8, r0 = ty * 8;
  float acc[8][8];
#pragma unroll
  for (int i = 0; i < 8; ++i)
#pragma unroll
    for (int j = 0; j < 8; ++j) acc[i][j] = 0.f;

#pragma unroll 4
  for (int k = 0; k < 128; ++k) {
    float a[8], w[8];
#pragma unroll
    for (int i = 0; i < 8; ++i) a[i] = xs[k][r0 + i];
#pragma unroll
    for (int j = 0; j < 8; ++j) w[j] = ws[k][c0 + j];
#pragma unroll
    for (int i = 0; i < 8; ++i)
#pragma unroll
      for (int j = 0; j < 8; ++j) acc[i][j] += a[i] * w[j];
  }

  // epilogue: + bias, store Z as float4
  float bv[8];
#pragma unroll
  for (int j = 0; j < 8; ++j) bv[j] = bias[c0 + j];
#pragma unroll
  for (int i = 0; i < 8; ++i) {
    int gr = base + r0 + i;
    if (gr < N) {
#pragma unroll
      for (int j4 = 0; j4 < 2; ++j4) {
        float4 v;
        v.x = acc[i][j4 * 4 + 0] + bv[j4 * 4 + 0];
        v.y = acc[i][j4 * 4 + 1] + bv[j4 * 4 + 1];
        v.z = acc[i][j4 * 4 + 2] + bv[j4 * 4 + 2];
        v.w = acc[i][j4 * 4 + 3] + bv[j4 * 4 + 3];
        reinterpret_cast<float4*>(Z)[(size_t)gr * 32 + (c0 >> 2) + j4] = v;
      }
    }
  }
}

__global__ __launch_bounds__(256) void node_e(
    const float* __restrict__ Z, const float* __restrict__ a_l,
    const float* __restrict__ a_r, float* __restrict__ el,
    float* __restrict__ er, int N) {
  int idx = blockIdx.x * 256 + threadIdx.x;   // n*4 + h
  if (idx >= N * 4) return;
  int n = idx >> 2, h = idx & 3;
  const float* zrow = Z + (size_t)n * 128;
  float sl = 0.f, sr = 0.f;
#pragma unroll 8
  for (int o = 0; o < 32; ++o) {
    float z = zrow[o * 4 + h];
    sl += z * a_l[o * 4 + h];
    sr += z * a_r[o * 4 + h];
  }
  el[idx] = sl;
  er[idx] = sr;
}

__global__ __launch_bounds__(256) void edge_ex(
    const int* __restrict__ row, const int* __restrict__ col,
    const float* __restrict__ el, const float* __restrict__ er,
    float* __restrict__ ex, float* __restrict__ denom, int E) {
  int idx = blockIdx.x * 256 + threadIdx.x;   // e*4 + h
  if (idx >= E * 4) return;
  int e = idx >> 2, h = idx & 3;
  int r = row[e], c = col[e];
  float v = el[r * 4 + h] + er[c * 4 + h];
  v = (v > 0.f) ? v : 0.2f * v;               // LeakyReLU(0.2)
  float xv = __expf(v);                       // no max-subtraction needed
  ex[idx] = xv;
  atomicAdd(&denom[r * 4 + h], xv);
}

__global__ __launch_bounds__(256) void inv_den(float* __restrict__ denom, int N) {
  int idx = blockIdx.x * 256 + threadIdx.x;
  if (idx >= N * 4) return;
  float d = denom[idx];
  denom[idx] = (d > 0.f) ? (1.0f / d) : 0.f;  // zero-degree nodes never read
}

__global__ __launch_bounds__(256) void scatter(
    const int* __restrict__ row, const int* __restrict__ col,
    const float* __restrict__ ex, const float* __restrict__ invden,
    const float* __restrict__ Z, float* __restrict__ out, int E) {
  size_t idx = (size_t)blockIdx.x * 256 + threadIdx.x;  // e*128 + c
  if (idx >= (size_t)E * 128) return;
  int e = (int)(idx >> 7);
  int c = (int)(idx & 127);
  int h = c & 3;
  int r = row[e];
  int cl = col[e];
  float alpha = ex[(size_t)e * 4 + h] * invden[(size_t)r * 4 + h];
  atomicAdd(&out[(size_t)r * 128 + c], alpha * Z[(size_t)cl * 128 + c]);
}

extern "C" void kernel_launch(void* const* d_in, const int* in_sizes, int n_in,
                              void* d_out, int out_size, void* d_ws, size_t ws_size,
                              hipStream_t stream) {
  const float* x   = (const float*)d_in[0];
  const int*   row = (const int*)d_in[1];
  const int*   col = (const int*)d_in[2];
  const float* W   = (const float*)d_in[3];
  const float* b   = (const float*)d_in[4];
  const float* a_l = (const float*)d_in[5];
  const float* a_r = (const float*)d_in[6];
  float* out = (float*)d_out;

  const int N = in_sizes[0] / 128;
  const int E = in_sizes[1];

  float* Z     = (float*)d_ws;
  float* el    = Z + (size_t)N * 128;
  float* er    = el + (size_t)N * 4;
  float* denom = er + (size_t)N * 4;
  float* ex    = denom + (size_t)N * 4;

  hipMemsetAsync(denom, 0, (size_t)N * 4 * sizeof(float), stream);
  hipMemsetAsync(out, 0, (size_t)N * 128 * sizeof(float), stream);

  gemm_z<<<(N + 127) / 128, 256, 0, stream>>>(x, W, b, Z, N);
  node_e<<<(N * 4 + 255) / 256, 256, 0, stream>>>(Z, a_l, a_r, el, er, N);
  edge_ex<<<(E * 4 + 255) / 256, 256, 0, stream>>>(row, col, el, er, ex, denom, E);
  inv_den<<<(N * 4 + 255) / 256, 256, 0, stream>>>(denom, N);

  int scatter_blocks = (int)(((size_t)E * 128 + 255) / 256);
  scatter<<<scatter_blocks, 256, 0, stream>>>(row, col, ex, denom, Z, out, E);
}

// Round 2
// 399.290 us; speedup vs baseline: 2.2166x; 2.2166x over previous
//
#include <hip/hip_runtime.h>
#include <math.h>

// ---------------------------------------------------------------------------
// GATConv forward, f32.  N=100000, E=1.6M, IN=128, OUT*HEADS=128 (OUT=32,H=4).
// Round 1: replace atomic scatter (677us) with destination-CSR gather.
//   1) gemm_z   : Z = x @ W^T + b
//   2) node_e   : el/er[n,h] = sum_o Z[n,o,h]*a[o,h]
//   3) deg_cnt  : deg[r]++ per edge
//   4) scan1/2/3: exclusive prefix sum -> base[], cursor[]=base[]
//   5) fill     : pos=cursor[r]++; sorted_col[pos]=col; sorted_ex[pos,0..3]=exp(lrelu(el[r]+er[c]))
//   6) gather   : per node n (128 thr): acc=sum ex*Z[col,c]; out = acc/sum(ex)
// Softmax max-subtraction dropped (shift-invariant; |e| <~ 6, exp safe).
// ---------------------------------------------------------------------------

__global__ __launch_bounds__(256) void gemm_z(
    const float* __restrict__ x, const float* __restrict__ W,
    const float* __restrict__ bias, float* __restrict__ Z, int N) {
  __shared__ float xs[128][132];
  __shared__ float ws[128][132];
  const int t = threadIdx.x;
  const int base = blockIdx.x * 128;

#pragma unroll
  for (int i = 0; i < 16; ++i) {
    int f4 = i * 256 + t;
    int c = f4 >> 5;
    int k = (f4 & 31) << 2;
    float4 v = reinterpret_cast<const float4*>(W)[f4];
    ws[k + 0][c] = v.x; ws[k + 1][c] = v.y;
    ws[k + 2][c] = v.z; ws[k + 3][c] = v.w;
  }
#pragma unroll
  for (int i = 0; i < 16; ++i) {
    int f4 = i * 256 + t;
    int r = f4 >> 5;
    int k = (f4 & 31) << 2;
    int gr = base + r;
    float4 v = make_float4(0.f, 0.f, 0.f, 0.f);
    if (gr < N) v = reinterpret_cast<const float4*>(x)[(size_t)gr * 32 + (f4 & 31)];
    xs[k + 0][r] = v.x; xs[k + 1][r] = v.y;
    xs[k + 2][r] = v.z; xs[k + 3][r] = v.w;
  }
  __syncthreads();

  const int tx = t & 15, ty = t >> 4;
  const int c0 = tx * 8, r0 = ty * 8;
  float acc[8][8];
#pragma unroll
  for (int i = 0; i < 8; ++i)
#pragma unroll
    for (int j = 0; j < 8; ++j) acc[i][j] = 0.f;

#pragma unroll 4
  for (int k = 0; k < 128; ++k) {
    float a[8], w[8];
#pragma unroll
    for (int i = 0; i < 8; ++i) a[i] = xs[k][r0 + i];
#pragma unroll
    for (int j = 0; j < 8; ++j) w[j] = ws[k][c0 + j];
#pragma unroll
    for (int i = 0; i < 8; ++i)
#pragma unroll
      for (int j = 0; j < 8; ++j) acc[i][j] += a[i] * w[j];
  }

  float bv[8];
#pragma unroll
  for (int j = 0; j < 8; ++j) bv[j] = bias[c0 + j];
#pragma unroll
  for (int i = 0; i < 8; ++i) {
    int gr = base + r0 + i;
    if (gr < N) {
#pragma unroll
      for (int j4 = 0; j4 < 2; ++j4) {
        float4 v;
        v.x = acc[i][j4 * 4 + 0] + bv[j4 * 4 + 0];
        v.y = acc[i][j4 * 4 + 1] + bv[j4 * 4 + 1];
        v.z = acc[i][j4 * 4 + 2] + bv[j4 * 4 + 2];
        v.w = acc[i][j4 * 4 + 3] + bv[j4 * 4 + 3];
        reinterpret_cast<float4*>(Z)[(size_t)gr * 32 + (c0 >> 2) + j4] = v;
      }
    }
  }
}

__global__ __launch_bounds__(256) void node_e(
    const float* __restrict__ Z, const float* __restrict__ a_l,
    const float* __restrict__ a_r, float* __restrict__ el,
    float* __restrict__ er, int N) {
  int idx = blockIdx.x * 256 + threadIdx.x;   // n*4 + h
  if (idx >= N * 4) return;
  int n = idx >> 2, h = idx & 3;
  const float* zrow = Z + (size_t)n * 128;
  float sl = 0.f, sr = 0.f;
#pragma unroll 8
  for (int o = 0; o < 32; ++o) {
    float z = zrow[o * 4 + h];
    sl += z * a_l[o * 4 + h];
    sr += z * a_r[o * 4 + h];
  }
  el[idx] = sl;
  er[idx] = sr;
}

__global__ __launch_bounds__(256) void deg_cnt(
    const int* __restrict__ row, int* __restrict__ deg, int E) {
  int e = blockIdx.x * 256 + threadIdx.x;
  if (e < E) atomicAdd(&deg[row[e]], 1);
}

__global__ __launch_bounds__(256) void scan1(
    const int* __restrict__ deg, int* __restrict__ base,
    int* __restrict__ bsum, int N) {
  __shared__ int s[256];
  int i = blockIdx.x * 256 + threadIdx.x;
  int v = (i < N) ? deg[i] : 0;
  s[threadIdx.x] = v;
  __syncthreads();
#pragma unroll
  for (int off = 1; off < 256; off <<= 1) {
    int t = (threadIdx.x >= off) ? s[threadIdx.x - off] : 0;
    __syncthreads();
    s[threadIdx.x] += t;
    __syncthreads();
  }
  if (i < N) base[i] = s[threadIdx.x] - v;   // exclusive
  if (threadIdx.x == 255) bsum[blockIdx.x] = s[255];
}

__global__ __launch_bounds__(512) void scan2(int* __restrict__ bsum, int NB) {
  __shared__ int s[512];
  int v = (threadIdx.x < NB) ? bsum[threadIdx.x] : 0;
  s[threadIdx.x] = v;
  __syncthreads();
#pragma unroll
  for (int off = 1; off < 512; off <<= 1) {
    int t = (threadIdx.x >= off) ? s[threadIdx.x - off] : 0;
    __syncthreads();
    s[threadIdx.x] += t;
    __syncthreads();
  }
  if (threadIdx.x < NB) bsum[threadIdx.x] = s[threadIdx.x] - v;  // exclusive
}

__global__ __launch_bounds__(256) void scan3(
    int* __restrict__ base, const int* __restrict__ bsum,
    int* __restrict__ cursor, int N) {
  int i = blockIdx.x * 256 + threadIdx.x;
  if (i < N) {
    int b = base[i] + bsum[i >> 8];
    base[i] = b;
    cursor[i] = b;
  }
}

__global__ __launch_bounds__(256) void fill(
    const int* __restrict__ row, const int* __restrict__ col,
    const float* __restrict__ el, const float* __restrict__ er,
    int* __restrict__ cursor, int* __restrict__ sorted_col,
    float* __restrict__ sorted_ex, int E) {
  int e = blockIdx.x * 256 + threadIdx.x;
  if (e >= E) return;
  int r = row[e], c = col[e];
  float4 l = reinterpret_cast<const float4*>(el)[r];
  float4 rr = reinterpret_cast<const float4*>(er)[c];
  float4 v;
  v.x = l.x + rr.x; v.y = l.y + rr.y; v.z = l.z + rr.z; v.w = l.w + rr.w;
  v.x = (v.x > 0.f) ? v.x : 0.2f * v.x;
  v.y = (v.y > 0.f) ? v.y : 0.2f * v.y;
  v.z = (v.z > 0.f) ? v.z : 0.2f * v.z;
  v.w = (v.w > 0.f) ? v.w : 0.2f * v.w;
  float4 ex4;
  ex4.x = __expf(v.x); ex4.y = __expf(v.y);
  ex4.z = __expf(v.z); ex4.w = __expf(v.w);
  int pos = atomicAdd(&cursor[r], 1);
  sorted_col[pos] = c;
  reinterpret_cast<float4*>(sorted_ex)[pos] = ex4;
}

__global__ __launch_bounds__(128) void gather(
    const int* __restrict__ base, const int* __restrict__ cursor,
    const int* __restrict__ sorted_col, const float* __restrict__ sorted_ex,
    const float* __restrict__ Z, float* __restrict__ out, int N) {
  int n = blockIdx.x;
  int c = threadIdx.x;
  int h = c & 3;
  int s = base[n];
  int e = cursor[n];          // == base[n] + deg[n]
  float acc = 0.f, sum = 0.f;
  int p = s;
  for (; p + 2 <= e; p += 2) {
    int c0 = sorted_col[p];
    int c1 = sorted_col[p + 1];
    float e0 = sorted_ex[(size_t)p * 4 + h];
    float e1 = sorted_ex[(size_t)(p + 1) * 4 + h];
    acc += e0 * Z[(size_t)c0 * 128 + c];
    acc += e1 * Z[(size_t)c1 * 128 + c];
    sum += e0 + e1;
  }
  if (p < e) {
    int c0 = sorted_col[p];
    float e0 = sorted_ex[(size_t)p * 4 + h];
    acc += e0 * Z[(size_t)c0 * 128 + c];
    sum += e0;
  }
  out[(size_t)n * 128 + c] = (sum > 0.f) ? (acc / sum) : 0.f;
}

extern "C" void kernel_launch(void* const* d_in, const int* in_sizes, int n_in,
                              void* d_out, int out_size, void* d_ws, size_t ws_size,
                              hipStream_t stream) {
  const float* x   = (const float*)d_in[0];
  const int*   row = (const int*)d_in[1];
  const int*   col = (const int*)d_in[2];
  const float* W   = (const float*)d_in[3];
  const float* b   = (const float*)d_in[4];
  const float* a_l = (const float*)d_in[5];
  const float* a_r = (const float*)d_in[6];
  float* out = (float*)d_out;

  const int N = in_sizes[0] / 128;
  const int E = in_sizes[1];
  const int NB = (N + 255) / 256;

  // workspace layout (floats); all offsets multiple of 4 elems -> 16B aligned
  float* Z         = (float*)d_ws;                    // N*128
  float* sorted_ex = Z + (size_t)N * 128;             // E*4
  int*   sorted_col= (int*)(sorted_ex + (size_t)E * 4); // E
  float* el        = (float*)(sorted_col + E);        // N*4
  float* er        = el + (size_t)N * 4;              // N*4
  int*   deg       = (int*)(er + (size_t)N * 4);      // N
  int*   base      = deg + N;                         // N
  int*   cursor    = base + N;                        // N
  int*   bsum      = cursor + N;                      // NB (<=512)

  hipMemsetAsync(deg, 0, (size_t)N * sizeof(int), stream);

  gemm_z<<<(N + 127) / 128, 256, 0, stream>>>(x, W, b, Z, N);
  node_e<<<(N * 4 + 255) / 256, 256, 0, stream>>>(Z, a_l, a_r, el, er, N);
  deg_cnt<<<(E + 255) / 256, 256, 0, stream>>>(row, deg, E);
  scan1<<<NB, 256, 0, stream>>>(deg, base, bsum, N);
  scan2<<<1, 512, 0, stream>>>(bsum, NB);
  scan3<<<NB, 256, 0, stream>>>(base, bsum, cursor, N);
  fill<<<(E + 255) / 256, 256, 0, stream>>>(row, col, el, er, cursor,
                                            sorted_col, sorted_ex, E);
  gather<<<N, 128, 0, stream>>>(base, cursor, sorted_col, sorted_ex, Z, out, N);
}

// Round 3
// 303.797 us; speedup vs baseline: 2.9134x; 1.3143x over previous
//
#include <hip/hip_runtime.h>
#include <hip/hip_bf16.h>
#include <math.h>

// ---------------------------------------------------------------------------
// GATConv forward.  N=100000, E=1.6M, IN=128, OUT*HEADS=128 (OUT=32, H=4).
// Round 3:
//   - gemm_z: MFMA bf16x3 (xh*Wh + xh*Wl + xl*Wh), W frags in registers,
//     x tile in 32KB swizzled LDS, fused el/er epilogue (factored through
//     wl = W^T a_l per head).  Z stored as bf16 (hi for gather, lo kept for
//     precision headroom).
//   - counting-sort CSR (deg/scan/fill) + per-node gather, gather reads Zh.
// ---------------------------------------------------------------------------

typedef __attribute__((ext_vector_type(8))) short bf16x8;
typedef __attribute__((ext_vector_type(4))) float f32x4;

__device__ __forceinline__ ushort f2bf(float f) {
  __hip_bfloat16 h = __float2bfloat16(f);   // RNE
  return __builtin_bit_cast(ushort, h);
}
__device__ __forceinline__ float bf2f(ushort u) {
  unsigned v = ((unsigned)u) << 16;
  return __builtin_bit_cast(float, v);
}

// wl[h*128+k] = sum_o W[o*4+h][k]*a_l[o*4+h]; cb[h]=sum_o b*a_l, cb[4+h] for r
__global__ __launch_bounds__(512) void prep_wl(
    const float* __restrict__ W, const float* __restrict__ b,
    const float* __restrict__ a_l, const float* __restrict__ a_r,
    float* __restrict__ wl, float* __restrict__ wr, float* __restrict__ cb) {
  int t = threadIdx.x;
  int h = t >> 7, k = t & 127;
  float sl = 0.f, sr = 0.f;
#pragma unroll 8
  for (int o = 0; o < 32; ++o) {
    float w = W[(size_t)(o * 4 + h) * 128 + k];
    sl += w * a_l[o * 4 + h];
    sr += w * a_r[o * 4 + h];
  }
  wl[t] = sl;
  wr[t] = sr;
  if (t < 8) {
    int hh = t & 3;
    const float* av = (t < 4) ? a_l : a_r;
    float s = 0.f;
    for (int o = 0; o < 32; ++o) s += b[o * 4 + hh] * av[o * 4 + hh];
    cb[t] = s;
  }
}

__global__ __launch_bounds__(256, 2) void gemm_z(
    const float* __restrict__ x, const float* __restrict__ W,
    const float* __restrict__ bias, const float* __restrict__ wl,
    const float* __restrict__ wr, const float* __restrict__ cb,
    ushort* __restrict__ Zh, ushort* __restrict__ Zl,
    float* __restrict__ el, float* __restrict__ er, int N) {
  __shared__ ushort xh[64 * 128];
  __shared__ ushort xl[64 * 128];
  const int t = threadIdx.x;
  const int lane = t & 63;
  const int wv = t >> 6;                 // wave id: owns channels wv*32..+31
  const int row0 = blockIdx.x * 64;
  const int l15 = lane & 15, l4 = lane >> 4;

  // ---- W fragments -> registers as bf16 hi/lo ----
  bf16x8 Bh[2][4], Bl[2][4];
#pragma unroll
  for (int ct = 0; ct < 2; ++ct) {
    int ch = wv * 32 + ct * 16 + l15;
#pragma unroll
    for (int kf = 0; kf < 4; ++kf) {
      int k0 = kf * 32 + l4 * 8;
      const float* wp = W + (size_t)ch * 128 + k0;
      float4 w0 = *(const float4*)(wp);
      float4 w1 = *(const float4*)(wp + 4);
      float wf[8] = {w0.x, w0.y, w0.z, w0.w, w1.x, w1.y, w1.z, w1.w};
      bf16x8 hi, lo;
#pragma unroll
      for (int j = 0; j < 8; ++j) {
        ushort hb = f2bf(wf[j]);
        hi[j] = (short)hb;
        lo[j] = (short)f2bf(wf[j] - bf2f(hb));
      }
      Bh[ct][kf] = hi;
      Bl[ct][kf] = lo;
    }
  }

  // ---- stage x tile (64 rows) -> LDS bf16 hi/lo, 16B-chunk XOR swizzle ----
#pragma unroll
  for (int i = 0; i < 8; ++i) {
    int f4 = i * 256 + t;                // 2048 float4s
    int r = f4 >> 5;
    int k = (f4 & 31) * 4;
    int gr = row0 + r;
    float4 v = make_float4(0.f, 0.f, 0.f, 0.f);
    if (gr < N) v = ((const float4*)x)[(size_t)gr * 32 + (f4 & 31)];
    float vf[4] = {v.x, v.y, v.z, v.w};
    ushort hs[4], ls[4];
#pragma unroll
    for (int j = 0; j < 4; ++j) {
      hs[j] = f2bf(vf[j]);
      ls[j] = f2bf(vf[j] - bf2f(hs[j]));
    }
    int idx = r * 128 + (k ^ ((r & 7) << 3));
    uint2 hv, lv;
    hv.x = hs[0] | ((unsigned)hs[1] << 16);
    hv.y = hs[2] | ((unsigned)hs[3] << 16);
    lv.x = ls[0] | ((unsigned)ls[1] << 16);
    lv.y = ls[2] | ((unsigned)ls[3] << 16);
    *(uint2*)&xh[idx] = hv;
    *(uint2*)&xl[idx] = lv;
  }
  __syncthreads();

  // ---- MFMA: 4 row-tiles x 2 ch-tiles x 4 k-frags x 3 products ----
  f32x4 acc[4][2];
#pragma unroll
  for (int rt = 0; rt < 4; ++rt)
#pragma unroll
    for (int ct = 0; ct < 2; ++ct) acc[rt][ct] = (f32x4){0.f, 0.f, 0.f, 0.f};

#pragma unroll
  for (int kf = 0; kf < 4; ++kf) {
#pragma unroll
    for (int rt = 0; rt < 4; ++rt) {
      int r = rt * 16 + l15;
      int k = kf * 32 + l4 * 8;
      int idx = r * 128 + (k ^ ((r & 7) << 3));
      bf16x8 ah = *(const bf16x8*)&xh[idx];
      bf16x8 al = *(const bf16x8*)&xl[idx];
#pragma unroll
      for (int ct = 0; ct < 2; ++ct) {
        acc[rt][ct] = __builtin_amdgcn_mfma_f32_16x16x32_bf16(ah, Bh[ct][kf], acc[rt][ct], 0, 0, 0);
        acc[rt][ct] = __builtin_amdgcn_mfma_f32_16x16x32_bf16(al, Bh[ct][kf], acc[rt][ct], 0, 0, 0);
        acc[rt][ct] = __builtin_amdgcn_mfma_f32_16x16x32_bf16(ah, Bl[ct][kf], acc[rt][ct], 0, 0, 0);
      }
    }
  }

  // ---- store Z (bf16 hi/lo); D layout: col=lane&15, row=(lane>>4)*4+j ----
  float bv[2];
  bv[0] = bias[wv * 32 + l15];
  bv[1] = bias[wv * 32 + 16 + l15];
#pragma unroll
  for (int rt = 0; rt < 4; ++rt) {
#pragma unroll
    for (int ct = 0; ct < 2; ++ct) {
      int ch = wv * 32 + ct * 16 + l15;
#pragma unroll
      for (int j = 0; j < 4; ++j) {
        int r = row0 + rt * 16 + l4 * 4 + j;
        if (r < N) {
          float v = acc[rt][ct][j] + bv[ct];
          ushort hb = f2bf(v);
          Zh[(size_t)r * 128 + ch] = hb;
          Zl[(size_t)r * 128 + ch] = f2bf(v - bf2f(hb));
        }
      }
    }
  }

  // ---- fused el/er from staged x (exact f32 via hi+lo) ----
  {
    int rowe = t & 63;
    int h = t >> 6;                       // wave-uniform head
    int gre = row0 + rowe;
    if (gre < N) {
      const float* wlp = wl + h * 128;
      const float* wrp = wr + h * 128;
      float sl = 0.f, sr = 0.f;
#pragma unroll
      for (int c = 0; c < 16; ++c) {
        int idx = rowe * 128 + ((c * 8) ^ ((rowe & 7) << 3));
        uint4 hv = *(const uint4*)&xh[idx];
        uint4 lv = *(const uint4*)&xl[idx];
        unsigned hw[4] = {hv.x, hv.y, hv.z, hv.w};
        unsigned lw[4] = {lv.x, lv.y, lv.z, lv.w};
#pragma unroll
        for (int q = 0; q < 4; ++q) {
          float x0 = bf2f((ushort)(hw[q] & 0xffff)) + bf2f((ushort)(lw[q] & 0xffff));
          float x1 = bf2f((ushort)(hw[q] >> 16)) + bf2f((ushort)(lw[q] >> 16));
          int k = c * 8 + q * 2;
          sl += x0 * wlp[k] + x1 * wlp[k + 1];
          sr += x0 * wrp[k] + x1 * wrp[k + 1];
        }
      }
      el[(size_t)gre * 4 + h] = sl + cb[h];
      er[(size_t)gre * 4 + h] = sr + cb[4 + h];
    }
  }
}

__global__ __launch_bounds__(256) void deg_cnt(
    const int* __restrict__ row, int* __restrict__ deg, int E) {
  int e = blockIdx.x * 256 + threadIdx.x;
  if (e < E) atomicAdd(&deg[row[e]], 1);
}

__global__ __launch_bounds__(256) void scan1(
    const int* __restrict__ deg, int* __restrict__ base,
    int* __restrict__ bsum, int N) {
  __shared__ int s[256];
  int i = blockIdx.x * 256 + threadIdx.x;
  int v = (i < N) ? deg[i] : 0;
  s[threadIdx.x] = v;
  __syncthreads();
#pragma unroll
  for (int off = 1; off < 256; off <<= 1) {
    int t = (threadIdx.x >= off) ? s[threadIdx.x - off] : 0;
    __syncthreads();
    s[threadIdx.x] += t;
    __syncthreads();
  }
  if (i < N) base[i] = s[threadIdx.x] - v;
  if (threadIdx.x == 255) bsum[blockIdx.x] = s[255];
}

__global__ __launch_bounds__(512) void scan2(int* __restrict__ bsum, int NB) {
  __shared__ int s[512];
  int v = (threadIdx.x < NB) ? bsum[threadIdx.x] : 0;
  s[threadIdx.x] = v;
  __syncthreads();
#pragma unroll
  for (int off = 1; off < 512; off <<= 1) {
    int t = (threadIdx.x >= off) ? s[threadIdx.x - off] : 0;
    __syncthreads();
    s[threadIdx.x] += t;
    __syncthreads();
  }
  if (threadIdx.x < NB) bsum[threadIdx.x] = s[threadIdx.x] - v;
}

__global__ __launch_bounds__(256) void scan3(
    int* __restrict__ base, const int* __restrict__ bsum,
    int* __restrict__ cursor, int N) {
  int i = blockIdx.x * 256 + threadIdx.x;
  if (i < N) {
    int b = base[i] + bsum[i >> 8];
    base[i] = b;
    cursor[i] = b;
  }
}

__global__ __launch_bounds__(256) void fill(
    const int* __restrict__ row, const int* __restrict__ col,
    const float* __restrict__ el, const float* __restrict__ er,
    int* __restrict__ cursor, int* __restrict__ sorted_col,
    float* __restrict__ sorted_ex, int E) {
  int e = blockIdx.x * 256 + threadIdx.x;
  if (e >= E) return;
  int r = row[e], c = col[e];
  float4 l = reinterpret_cast<const float4*>(el)[r];
  float4 rr = reinterpret_cast<const float4*>(er)[c];
  float4 v;
  v.x = l.x + rr.x; v.y = l.y + rr.y; v.z = l.z + rr.z; v.w = l.w + rr.w;
  v.x = (v.x > 0.f) ? v.x : 0.2f * v.x;
  v.y = (v.y > 0.f) ? v.y : 0.2f * v.y;
  v.z = (v.z > 0.f) ? v.z : 0.2f * v.z;
  v.w = (v.w > 0.f) ? v.w : 0.2f * v.w;
  float4 ex4;
  ex4.x = __expf(v.x); ex4.y = __expf(v.y);
  ex4.z = __expf(v.z); ex4.w = __expf(v.w);
  int pos = atomicAdd(&cursor[r], 1);
  sorted_col[pos] = c;
  reinterpret_cast<float4*>(sorted_ex)[pos] = ex4;
}

__global__ __launch_bounds__(128) void gather(
    const int* __restrict__ base, const int* __restrict__ cursor,
    const int* __restrict__ sorted_col, const float* __restrict__ sorted_ex,
    const ushort* __restrict__ Zh, float* __restrict__ out, int N) {
  int n = blockIdx.x;
  int c = threadIdx.x;
  int h = c & 3;
  int s = base[n];
  int e = cursor[n];
  float acc = 0.f, sum = 0.f;
  int p = s;
  for (; p + 4 <= e; p += 4) {
    int c0 = sorted_col[p], c1 = sorted_col[p + 1];
    int c2 = sorted_col[p + 2], c3 = sorted_col[p + 3];
    float e0 = sorted_ex[(size_t)p * 4 + h];
    float e1 = sorted_ex[(size_t)(p + 1) * 4 + h];
    float e2 = sorted_ex[(size_t)(p + 2) * 4 + h];
    float e3 = sorted_ex[(size_t)(p + 3) * 4 + h];
    float z0 = bf2f(Zh[(size_t)c0 * 128 + c]);
    float z1 = bf2f(Zh[(size_t)c1 * 128 + c]);
    float z2 = bf2f(Zh[(size_t)c2 * 128 + c]);
    float z3 = bf2f(Zh[(size_t)c3 * 128 + c]);
    acc += e0 * z0 + e1 * z1 + e2 * z2 + e3 * z3;
    sum += (e0 + e1) + (e2 + e3);
  }
  for (; p < e; ++p) {
    int c0 = sorted_col[p];
    float e0 = sorted_ex[(size_t)p * 4 + h];
    acc += e0 * bf2f(Zh[(size_t)c0 * 128 + c]);
    sum += e0;
  }
  out[(size_t)n * 128 + c] = (sum > 0.f) ? (acc / sum) : 0.f;
}

extern "C" void kernel_launch(void* const* d_in, const int* in_sizes, int n_in,
                              void* d_out, int out_size, void* d_ws, size_t ws_size,
                              hipStream_t stream) {
  const float* x   = (const float*)d_in[0];
  const int*   row = (const int*)d_in[1];
  const int*   col = (const int*)d_in[2];
  const float* W   = (const float*)d_in[3];
  const float* b   = (const float*)d_in[4];
  const float* a_l = (const float*)d_in[5];
  const float* a_r = (const float*)d_in[6];
  float* out = (float*)d_out;

  const int N = in_sizes[0] / 128;
  const int E = in_sizes[1];
  const int NB = (N + 255) / 256;

  char* w = (char*)d_ws;
  ushort* Zh       = (ushort*)w;             w += (size_t)N * 128 * 2;
  ushort* Zl       = (ushort*)w;             w += (size_t)N * 128 * 2;
  float* sorted_ex = (float*)w;              w += (size_t)E * 4 * 4;
  int*   sorted_col= (int*)w;                w += (size_t)E * 4;
  float* el        = (float*)w;              w += (size_t)N * 4 * 4;
  float* er        = (float*)w;              w += (size_t)N * 4 * 4;
  int*   deg       = (int*)w;                w += (size_t)N * 4;
  int*   base      = (int*)w;                w += (size_t)N * 4;
  int*   cursor    = (int*)w;                w += (size_t)N * 4;
  int*   bsum      = (int*)w;                w += 512 * 4;
  float* wl        = (float*)w;              w += 512 * 4;
  float* wr        = (float*)w;              w += 512 * 4;
  float* cb        = (float*)w;              w += 8 * 4;

  hipMemsetAsync(deg, 0, (size_t)N * sizeof(int), stream);

  prep_wl<<<1, 512, 0, stream>>>(W, b, a_l, a_r, wl, wr, cb);
  gemm_z<<<(N + 63) / 64, 256, 0, stream>>>(x, W, b, wl, wr, cb, Zh, Zl, el, er, N);
  deg_cnt<<<(E + 255) / 256, 256, 0, stream>>>(row, deg, E);
  scan1<<<NB, 256, 0, stream>>>(deg, base, bsum, N);
  scan2<<<1, 512, 0, stream>>>(bsum, NB);
  scan3<<<NB, 256, 0, stream>>>(base, bsum, cursor, N);
  fill<<<(E + 255) / 256, 256, 0, stream>>>(row, col, el, er, cursor,
                                            sorted_col, sorted_ex, E);
  gather<<<N, 128, 0, stream>>>(base, cursor, sorted_col, sorted_ex, Zh, out, N);
}

// Round 4
// 245.465 us; speedup vs baseline: 3.6057x; 1.2376x over previous
//
#include <hip/hip_runtime.h>
#include <hip/hip_bf16.h>
#include <math.h>

// ---------------------------------------------------------------------------
// GATConv forward.  N=100000, E=1.6M, IN=128, OUT*HEADS=128 (OUT=32, H=4).
// Round 4:
//   - gemm_z: MFMA bf16x3, W frags in registers, x in swizzled LDS, fused
//     el/er epilogue.  Z stored bf16 (hi only -- Zl dropped, never read).
//   - CSR build: deg_cnt keeps atomicAdd return as rank[e]; fill is then an
//     atomic-free 4B scatter.  sorted_ex eliminated entirely; gather
//     recomputes exp(lrelu(el+er)) on the fly (er is L2-resident).
//   - gather: 1 wave per node, 2 adjacent channels per lane (same head pair),
//     coalesced 4B/lane Zh row reads, float2 out writes.
// ---------------------------------------------------------------------------

typedef __attribute__((ext_vector_type(8))) short bf16x8;
typedef __attribute__((ext_vector_type(4))) float f32x4;

__device__ __forceinline__ ushort f2bf(float f) {
  __hip_bfloat16 h = __float2bfloat16(f);   // RNE
  return __builtin_bit_cast(ushort, h);
}
__device__ __forceinline__ float bf2f(ushort u) {
  unsigned v = ((unsigned)u) << 16;
  return __builtin_bit_cast(float, v);
}

// wl[h*128+k] = sum_o W[o*4+h][k]*a_l[o*4+h]; cb[h]=sum_o b*a_l, cb[4+h] for r
__global__ __launch_bounds__(512) void prep_wl(
    const float* __restrict__ W, const float* __restrict__ b,
    const float* __restrict__ a_l, const float* __restrict__ a_r,
    float* __restrict__ wl, float* __restrict__ wr, float* __restrict__ cb) {
  int t = threadIdx.x;
  int h = t >> 7, k = t & 127;
  float sl = 0.f, sr = 0.f;
#pragma unroll 8
  for (int o = 0; o < 32; ++o) {
    float w = W[(size_t)(o * 4 + h) * 128 + k];
    sl += w * a_l[o * 4 + h];
    sr += w * a_r[o * 4 + h];
  }
  wl[t] = sl;
  wr[t] = sr;
  if (t < 8) {
    int hh = t & 3;
    const float* av = (t < 4) ? a_l : a_r;
    float s = 0.f;
    for (int o = 0; o < 32; ++o) s += b[o * 4 + hh] * av[o * 4 + hh];
    cb[t] = s;
  }
}

__global__ __launch_bounds__(256, 2) void gemm_z(
    const float* __restrict__ x, const float* __restrict__ W,
    const float* __restrict__ bias, const float* __restrict__ wl,
    const float* __restrict__ wr, const float* __restrict__ cb,
    ushort* __restrict__ Zh,
    float* __restrict__ el, float* __restrict__ er, int N) {
  __shared__ ushort xh[64 * 128];
  __shared__ ushort xl[64 * 128];
  const int t = threadIdx.x;
  const int lane = t & 63;
  const int wv = t >> 6;                 // wave id: owns channels wv*32..+31
  const int row0 = blockIdx.x * 64;
  const int l15 = lane & 15, l4 = lane >> 4;

  // ---- W fragments -> registers as bf16 hi/lo ----
  bf16x8 Bh[2][4], Bl[2][4];
#pragma unroll
  for (int ct = 0; ct < 2; ++ct) {
    int ch = wv * 32 + ct * 16 + l15;
#pragma unroll
    for (int kf = 0; kf < 4; ++kf) {
      int k0 = kf * 32 + l4 * 8;
      const float* wp = W + (size_t)ch * 128 + k0;
      float4 w0 = *(const float4*)(wp);
      float4 w1 = *(const float4*)(wp + 4);
      float wf[8] = {w0.x, w0.y, w0.z, w0.w, w1.x, w1.y, w1.z, w1.w};
      bf16x8 hi, lo;
#pragma unroll
      for (int j = 0; j < 8; ++j) {
        ushort hb = f2bf(wf[j]);
        hi[j] = (short)hb;
        lo[j] = (short)f2bf(wf[j] - bf2f(hb));
      }
      Bh[ct][kf] = hi;
      Bl[ct][kf] = lo;
    }
  }

  // ---- stage x tile (64 rows) -> LDS bf16 hi/lo, 16B-chunk XOR swizzle ----
#pragma unroll
  for (int i = 0; i < 8; ++i) {
    int f4 = i * 256 + t;                // 2048 float4s
    int r = f4 >> 5;
    int k = (f4 & 31) * 4;
    int gr = row0 + r;
    float4 v = make_float4(0.f, 0.f, 0.f, 0.f);
    if (gr < N) v = ((const float4*)x)[(size_t)gr * 32 + (f4 & 31)];
    float vf[4] = {v.x, v.y, v.z, v.w};
    ushort hs[4], ls[4];
#pragma unroll
    for (int j = 0; j < 4; ++j) {
      hs[j] = f2bf(vf[j]);
      ls[j] = f2bf(vf[j] - bf2f(hs[j]));
    }
    int idx = r * 128 + (k ^ ((r & 7) << 3));
    uint2 hv, lv;
    hv.x = hs[0] | ((unsigned)hs[1] << 16);
    hv.y = hs[2] | ((unsigned)hs[3] << 16);
    lv.x = ls[0] | ((unsigned)ls[1] << 16);
    lv.y = ls[2] | ((unsigned)ls[3] << 16);
    *(uint2*)&xh[idx] = hv;
    *(uint2*)&xl[idx] = lv;
  }
  __syncthreads();

  // ---- MFMA: 4 row-tiles x 2 ch-tiles x 4 k-frags x 3 products ----
  f32x4 acc[4][2];
#pragma unroll
  for (int rt = 0; rt < 4; ++rt)
#pragma unroll
    for (int ct = 0; ct < 2; ++ct) acc[rt][ct] = (f32x4){0.f, 0.f, 0.f, 0.f};

#pragma unroll
  for (int kf = 0; kf < 4; ++kf) {
#pragma unroll
    for (int rt = 0; rt < 4; ++rt) {
      int r = rt * 16 + l15;
      int k = kf * 32 + l4 * 8;
      int idx = r * 128 + (k ^ ((r & 7) << 3));
      bf16x8 ah = *(const bf16x8*)&xh[idx];
      bf16x8 al = *(const bf16x8*)&xl[idx];
#pragma unroll
      for (int ct = 0; ct < 2; ++ct) {
        acc[rt][ct] = __builtin_amdgcn_mfma_f32_16x16x32_bf16(ah, Bh[ct][kf], acc[rt][ct], 0, 0, 0);
        acc[rt][ct] = __builtin_amdgcn_mfma_f32_16x16x32_bf16(al, Bh[ct][kf], acc[rt][ct], 0, 0, 0);
        acc[rt][ct] = __builtin_amdgcn_mfma_f32_16x16x32_bf16(ah, Bl[ct][kf], acc[rt][ct], 0, 0, 0);
      }
    }
  }

  // ---- store Zh; D layout: col=lane&15, row=(lane>>4)*4+j ----
  float bv[2];
  bv[0] = bias[wv * 32 + l15];
  bv[1] = bias[wv * 32 + 16 + l15];
#pragma unroll
  for (int rt = 0; rt < 4; ++rt) {
#pragma unroll
    for (int ct = 0; ct < 2; ++ct) {
      int ch = wv * 32 + ct * 16 + l15;
#pragma unroll
      for (int j = 0; j < 4; ++j) {
        int r = row0 + rt * 16 + l4 * 4 + j;
        if (r < N) {
          float v = acc[rt][ct][j] + bv[ct];
          Zh[(size_t)r * 128 + ch] = f2bf(v);
        }
      }
    }
  }

  // ---- fused el/er from staged x (exact f32 via hi+lo) ----
  {
    int rowe = t & 63;
    int h = t >> 6;                       // wave-uniform head
    int gre = row0 + rowe;
    if (gre < N) {
      const float* wlp = wl + h * 128;
      const float* wrp = wr + h * 128;
      float sl = 0.f, sr = 0.f;
#pragma unroll
      for (int c = 0; c < 16; ++c) {
        int idx = rowe * 128 + ((c * 8) ^ ((rowe & 7) << 3));
        uint4 hv = *(const uint4*)&xh[idx];
        uint4 lv = *(const uint4*)&xl[idx];
        unsigned hw[4] = {hv.x, hv.y, hv.z, hv.w};
        unsigned lw[4] = {lv.x, lv.y, lv.z, lv.w};
#pragma unroll
        for (int q = 0; q < 4; ++q) {
          float x0 = bf2f((ushort)(hw[q] & 0xffff)) + bf2f((ushort)(lw[q] & 0xffff));
          float x1 = bf2f((ushort)(hw[q] >> 16)) + bf2f((ushort)(lw[q] >> 16));
          int k = c * 8 + q * 2;
          sl += x0 * wlp[k] + x1 * wlp[k + 1];
          sr += x0 * wrp[k] + x1 * wrp[k + 1];
        }
      }
      el[(size_t)gre * 4 + h] = sl + cb[h];
      er[(size_t)gre * 4 + h] = sr + cb[4 + h];
    }
  }
}

__global__ __launch_bounds__(256) void deg_cnt(
    const int* __restrict__ row, int* __restrict__ deg,
    int* __restrict__ rank, int E) {
  int e = blockIdx.x * 256 + threadIdx.x;
  if (e < E) rank[e] = atomicAdd(&deg[row[e]], 1);
}

__global__ __launch_bounds__(256) void scan1(
    const int* __restrict__ deg, int* __restrict__ base,
    int* __restrict__ bsum, int N) {
  __shared__ int s[256];
  int i = blockIdx.x * 256 + threadIdx.x;
  int v = (i < N) ? deg[i] : 0;
  s[threadIdx.x] = v;
  __syncthreads();
#pragma unroll
  for (int off = 1; off < 256; off <<= 1) {
    int t = (threadIdx.x >= off) ? s[threadIdx.x - off] : 0;
    __syncthreads();
    s[threadIdx.x] += t;
    __syncthreads();
  }
  if (i < N) base[i] = s[threadIdx.x] - v;
  if (threadIdx.x == 255) bsum[blockIdx.x] = s[255];
}

__global__ __launch_bounds__(512) void scan2(int* __restrict__ bsum, int NB) {
  __shared__ int s[512];
  int v = (threadIdx.x < NB) ? bsum[threadIdx.x] : 0;
  s[threadIdx.x] = v;
  __syncthreads();
#pragma unroll
  for (int off = 1; off < 512; off <<= 1) {
    int t = (threadIdx.x >= off) ? s[threadIdx.x - off] : 0;
    __syncthreads();
    s[threadIdx.x] += t;
    __syncthreads();
  }
  if (threadIdx.x < NB) bsum[threadIdx.x] = s[threadIdx.x] - v;
}

__global__ __launch_bounds__(256) void scan3(
    int* __restrict__ base, const int* __restrict__ bsum, int N) {
  int i = blockIdx.x * 256 + threadIdx.x;
  if (i < N) base[i] = base[i] + bsum[i >> 8];
}

__global__ __launch_bounds__(256) void fill(
    const int* __restrict__ row, const int* __restrict__ col,
    const int* __restrict__ rank, const int* __restrict__ base,
    int* __restrict__ sorted_col, int E) {
  int e = blockIdx.x * 256 + threadIdx.x;
  if (e < E) sorted_col[base[row[e]] + rank[e]] = col[e];
}

__global__ __launch_bounds__(256) void gather(
    const int* __restrict__ base, const int* __restrict__ deg,
    const int* __restrict__ sorted_col, const float* __restrict__ el,
    const float* __restrict__ er, const ushort* __restrict__ Zh,
    float* __restrict__ out, int N) {
  int t = threadIdx.x;
  int lane = t & 63;
  int n = blockIdx.x * 4 + (t >> 6);
  if (n >= N) return;
  int c0 = lane * 2;            // channels c0, c0+1  (same head pair)
  int h0 = c0 & 3;              // heads h0, h0+1
  int s = base[n];
  int d = deg[n];
  float2 elv = *(const float2*)&el[(size_t)n * 4 + h0];
  float acc0 = 0.f, acc1 = 0.f, sum0 = 0.f, sum1 = 0.f;
#pragma unroll 4
  for (int p = s; p < s + d; ++p) {
    int cl = sorted_col[p];
    float2 erv = *(const float2*)&er[(size_t)cl * 4 + h0];
    float e0 = elv.x + erv.x;
    float e1 = elv.y + erv.y;
    e0 = (e0 > 0.f) ? e0 : 0.2f * e0;
    e1 = (e1 > 0.f) ? e1 : 0.2f * e1;
    float x0 = __expf(e0), x1 = __expf(e1);
    unsigned zz = *(const unsigned*)&Zh[(size_t)cl * 128 + c0];
    acc0 += x0 * bf2f((ushort)(zz & 0xffff));
    acc1 += x1 * bf2f((ushort)(zz >> 16));
    sum0 += x0;
    sum1 += x1;
  }
  float2 o;
  o.x = (sum0 > 0.f) ? acc0 / sum0 : 0.f;
  o.y = (sum1 > 0.f) ? acc1 / sum1 : 0.f;
  *(float2*)&out[(size_t)n * 128 + c0] = o;
}

extern "C" void kernel_launch(void* const* d_in, const int* in_sizes, int n_in,
                              void* d_out, int out_size, void* d_ws, size_t ws_size,
                              hipStream_t stream) {
  const float* x   = (const float*)d_in[0];
  const int*   row = (const int*)d_in[1];
  const int*   col = (const int*)d_in[2];
  const float* W   = (const float*)d_in[3];
  const float* b   = (const float*)d_in[4];
  const float* a_l = (const float*)d_in[5];
  const float* a_r = (const float*)d_in[6];
  float* out = (float*)d_out;

  const int N = in_sizes[0] / 128;
  const int E = in_sizes[1];
  const int NB = (N + 255) / 256;

  char* w = (char*)d_ws;
  ushort* Zh       = (ushort*)w;             w += (size_t)N * 128 * 2;
  int*   sorted_col= (int*)w;                w += (size_t)E * 4;
  int*   rank      = (int*)w;                w += (size_t)E * 4;
  float* el        = (float*)w;              w += (size_t)N * 4 * 4;
  float* er        = (float*)w;              w += (size_t)N * 4 * 4;
  int*   deg       = (int*)w;                w += (size_t)N * 4;
  int*   base      = (int*)w;                w += (size_t)N * 4;
  int*   bsum      = (int*)w;                w += 512 * 4;
  float* wl        = (float*)w;              w += 512 * 4;
  float* wr        = (float*)w;              w += 512 * 4;
  float* cb        = (float*)w;              w += 8 * 4;

  hipMemsetAsync(deg, 0, (size_t)N * sizeof(int), stream);

  prep_wl<<<1, 512, 0, stream>>>(W, b, a_l, a_r, wl, wr, cb);
  gemm_z<<<(N + 63) / 64, 256, 0, stream>>>(x, W, b, wl, wr, cb, Zh, el, er, N);
  deg_cnt<<<(E + 255) / 256, 256, 0, stream>>>(row, deg, rank, E);
  scan1<<<NB, 256, 0, stream>>>(deg, base, bsum, N);
  scan2<<<1, 512, 0, stream>>>(bsum, NB);
  scan3<<<NB, 256, 0, stream>>>(base, bsum, N);
  fill<<<(E + 255) / 256, 256, 0, stream>>>(row, col, rank, base, sorted_col, E);
  gather<<<(N + 3) / 4, 256, 0, stream>>>(base, deg, sorted_col, el, er, Zh, out, N);
}

// Round 5
// 233.620 us; speedup vs baseline: 3.7885x; 1.0507x over previous
//
#include <hip/hip_runtime.h>
#include <hip/hip_bf16.h>
#include <math.h>

// ---------------------------------------------------------------------------
// GATConv forward.  N=100000, E=1.6M, IN=128, OUT*HEADS=128 (OUT=32, H=4).
// Round 5:
//   - Zh stored HEAD-MAJOR: Zh[n*128 + h*32 + o]  (ch = o*4+h in ref layout).
//   - gemm_z: MFMA bf16x3 only (el/er epilogue + prep_wl deleted).
//   - node_e: el/er = Z . a computed from head-major Zh (contiguous reads).
//   - CSR: deg_cnt(rank) -> scan1/scan2 -> fill (scan3 fused via bsum[r>>8]).
//   - gather: 1 wave/node, lane = (head, 2 same-head channels) -> 1 exp per
//     lane-edge, 1 divide per node, 32-bit address math.
// ---------------------------------------------------------------------------

typedef __attribute__((ext_vector_type(8))) short bf16x8;
typedef __attribute__((ext_vector_type(4))) float f32x4;

__device__ __forceinline__ ushort f2bf(float f) {
  __hip_bfloat16 h = __float2bfloat16(f);   // RNE
  return __builtin_bit_cast(ushort, h);
}
__device__ __forceinline__ float bf2f(ushort u) {
  unsigned v = ((unsigned)u) << 16;
  return __builtin_bit_cast(float, v);
}

__global__ __launch_bounds__(256, 2) void gemm_z(
    const float* __restrict__ x, const float* __restrict__ W,
    const float* __restrict__ bias, ushort* __restrict__ Zh, int N) {
  __shared__ ushort xh[64 * 128];
  __shared__ ushort xl[64 * 128];
  const int t = threadIdx.x;
  const int lane = t & 63;
  const int wv = t >> 6;                 // wave id: owns channels wv*32..+31
  const int row0 = blockIdx.x * 64;
  const int l15 = lane & 15, l4 = lane >> 4;

  // ---- W fragments -> registers as bf16 hi/lo ----
  bf16x8 Bh[2][4], Bl[2][4];
#pragma unroll
  for (int ct = 0; ct < 2; ++ct) {
    int ch = wv * 32 + ct * 16 + l15;
#pragma unroll
    for (int kf = 0; kf < 4; ++kf) {
      int k0 = kf * 32 + l4 * 8;
      const float* wp = W + (size_t)ch * 128 + k0;
      float4 w0 = *(const float4*)(wp);
      float4 w1 = *(const float4*)(wp + 4);
      float wf[8] = {w0.x, w0.y, w0.z, w0.w, w1.x, w1.y, w1.z, w1.w};
      bf16x8 hi, lo;
#pragma unroll
      for (int j = 0; j < 8; ++j) {
        ushort hb = f2bf(wf[j]);
        hi[j] = (short)hb;
        lo[j] = (short)f2bf(wf[j] - bf2f(hb));
      }
      Bh[ct][kf] = hi;
      Bl[ct][kf] = lo;
    }
  }

  // ---- stage x tile (64 rows) -> LDS bf16 hi/lo, 16B-chunk XOR swizzle ----
#pragma unroll
  for (int i = 0; i < 8; ++i) {
    int f4 = i * 256 + t;                // 2048 float4s
    int r = f4 >> 5;
    int k = (f4 & 31) * 4;
    int gr = row0 + r;
    float4 v = make_float4(0.f, 0.f, 0.f, 0.f);
    if (gr < N) v = ((const float4*)x)[(size_t)gr * 32 + (f4 & 31)];
    float vf[4] = {v.x, v.y, v.z, v.w};
    ushort hs[4], ls[4];
#pragma unroll
    for (int j = 0; j < 4; ++j) {
      hs[j] = f2bf(vf[j]);
      ls[j] = f2bf(vf[j] - bf2f(hs[j]));
    }
    int idx = r * 128 + (k ^ ((r & 7) << 3));
    uint2 hv, lv;
    hv.x = hs[0] | ((unsigned)hs[1] << 16);
    hv.y = hs[2] | ((unsigned)hs[3] << 16);
    lv.x = ls[0] | ((unsigned)ls[1] << 16);
    lv.y = ls[2] | ((unsigned)ls[3] << 16);
    *(uint2*)&xh[idx] = hv;
    *(uint2*)&xl[idx] = lv;
  }
  __syncthreads();

  // ---- MFMA: 4 row-tiles x 2 ch-tiles x 4 k-frags x 3 products ----
  f32x4 acc[4][2];
#pragma unroll
  for (int rt = 0; rt < 4; ++rt)
#pragma unroll
    for (int ct = 0; ct < 2; ++ct) acc[rt][ct] = (f32x4){0.f, 0.f, 0.f, 0.f};

#pragma unroll
  for (int kf = 0; kf < 4; ++kf) {
#pragma unroll
    for (int rt = 0; rt < 4; ++rt) {
      int r = rt * 16 + l15;
      int k = kf * 32 + l4 * 8;
      int idx = r * 128 + (k ^ ((r & 7) << 3));
      bf16x8 ah = *(const bf16x8*)&xh[idx];
      bf16x8 al = *(const bf16x8*)&xl[idx];
#pragma unroll
      for (int ct = 0; ct < 2; ++ct) {
        acc[rt][ct] = __builtin_amdgcn_mfma_f32_16x16x32_bf16(ah, Bh[ct][kf], acc[rt][ct], 0, 0, 0);
        acc[rt][ct] = __builtin_amdgcn_mfma_f32_16x16x32_bf16(al, Bh[ct][kf], acc[rt][ct], 0, 0, 0);
        acc[rt][ct] = __builtin_amdgcn_mfma_f32_16x16x32_bf16(ah, Bl[ct][kf], acc[rt][ct], 0, 0, 0);
      }
    }
  }

  // ---- store Zh head-major; D layout: col=lane&15, row=(lane>>4)*4+j ----
  float bv[2];
  bv[0] = bias[wv * 32 + l15];
  bv[1] = bias[wv * 32 + 16 + l15];
#pragma unroll
  for (int rt = 0; rt < 4; ++rt) {
#pragma unroll
    for (int ct = 0; ct < 2; ++ct) {
      int ch = wv * 32 + ct * 16 + l15;       // ch = o*4+h (ref channel)
      unsigned zc = (unsigned)((ch & 3) * 32 + (ch >> 2));  // head-major
#pragma unroll
      for (int j = 0; j < 4; ++j) {
        int r = row0 + rt * 16 + l4 * 4 + j;
        if (r < N) {
          float v = acc[rt][ct][j] + bv[ct];
          Zh[(unsigned)r * 128 + zc] = f2bf(v);
        }
      }
    }
  }
}

// el/er[n,h] = sum_o Zh[n,h,o] * a[o*4+h]   (Z already includes bias)
__global__ __launch_bounds__(256) void node_e(
    const ushort* __restrict__ Zh, const float* __restrict__ a_l,
    const float* __restrict__ a_r, float* __restrict__ el,
    float* __restrict__ er, int N4) {
  __shared__ float sal[128], sar[128];
  int t = threadIdx.x;
  if (t < 128) { sal[t] = a_l[t]; sar[t] = a_r[t]; }
  __syncthreads();
  int idx = blockIdx.x * 256 + t;       // n*4 + h
  if (idx >= N4) return;
  int n = idx >> 2, h = idx & 3;
  const ushort* zp = Zh + (unsigned)n * 128 + h * 32;
  float sl = 0.f, sr = 0.f;
#pragma unroll
  for (int q = 0; q < 8; ++q) {
    uint2 zz = *(const uint2*)&zp[q * 4];
    float z0 = bf2f((ushort)(zz.x & 0xffff));
    float z1 = bf2f((ushort)(zz.x >> 16));
    float z2 = bf2f((ushort)(zz.y & 0xffff));
    float z3 = bf2f((ushort)(zz.y >> 16));
    int o = q * 4;
    sl += z0 * sal[(o + 0) * 4 + h] + z1 * sal[(o + 1) * 4 + h]
        + z2 * sal[(o + 2) * 4 + h] + z3 * sal[(o + 3) * 4 + h];
    sr += z0 * sar[(o + 0) * 4 + h] + z1 * sar[(o + 1) * 4 + h]
        + z2 * sar[(o + 2) * 4 + h] + z3 * sar[(o + 3) * 4 + h];
  }
  el[idx] = sl;
  er[idx] = sr;
}

__global__ __launch_bounds__(256) void deg_cnt(
    const int* __restrict__ row, int* __restrict__ deg,
    int* __restrict__ rank, int E) {
  int e = blockIdx.x * 256 + threadIdx.x;
  if (e < E) rank[e] = atomicAdd(&deg[row[e]], 1);
}

__global__ __launch_bounds__(256) void scan1(
    const int* __restrict__ deg, int* __restrict__ base,
    int* __restrict__ bsum, int N) {
  __shared__ int s[256];
  int i = blockIdx.x * 256 + threadIdx.x;
  int v = (i < N) ? deg[i] : 0;
  s[threadIdx.x] = v;
  __syncthreads();
#pragma unroll
  for (int off = 1; off < 256; off <<= 1) {
    int t = (threadIdx.x >= off) ? s[threadIdx.x - off] : 0;
    __syncthreads();
    s[threadIdx.x] += t;
    __syncthreads();
  }
  if (i < N) base[i] = s[threadIdx.x] - v;
  if (threadIdx.x == 255) bsum[blockIdx.x] = s[255];
}

__global__ __launch_bounds__(512) void scan2(int* __restrict__ bsum, int NB) {
  __shared__ int s[512];
  int v = (threadIdx.x < NB) ? bsum[threadIdx.x] : 0;
  s[threadIdx.x] = v;
  __syncthreads();
#pragma unroll
  for (int off = 1; off < 512; off <<= 1) {
    int t = (threadIdx.x >= off) ? s[threadIdx.x - off] : 0;
    __syncthreads();
    s[threadIdx.x] += t;
    __syncthreads();
  }
  if (threadIdx.x < NB) bsum[threadIdx.x] = s[threadIdx.x] - v;
}

__global__ __launch_bounds__(256) void fill(
    const int* __restrict__ row, const int* __restrict__ col,
    const int* __restrict__ rank, const int* __restrict__ base,
    const int* __restrict__ bsum, int* __restrict__ sorted_col, int E) {
  int e = blockIdx.x * 256 + threadIdx.x;
  if (e < E) {
    int r = row[e];
    sorted_col[base[r] + bsum[r >> 8] + rank[e]] = col[e];
  }
}

__global__ __launch_bounds__(256) void gather(
    const int* __restrict__ base, const int* __restrict__ bsum,
    const int* __restrict__ deg, const int* __restrict__ sorted_col,
    const float* __restrict__ el, const float* __restrict__ er,
    const ushort* __restrict__ Zh, float* __restrict__ out, int N) {
  int t = threadIdx.x;
  int lane = t & 63;
  int n = blockIdx.x * 4 + (t >> 6);
  if (n >= N) return;
  int h = lane >> 4;                 // head (16 lanes each)
  int o0 = (lane & 15) << 1;         // 2 same-head output dims
  int s = base[n] + bsum[n >> 8];
  int d = deg[n];
  float elv = el[(unsigned)(n << 2) + h];
  unsigned zoff = (unsigned)(h * 32 + o0);
  float acc0 = 0.f, acc1 = 0.f, sum = 0.f;
#pragma unroll 4
  for (int p = s; p < s + d; ++p) {
    int cl = sorted_col[p];
    float e = elv + er[((unsigned)cl << 2) + h];
    e = fmaxf(e, 0.2f * e);          // LeakyReLU(0.2)
    float xv = __expf(e);
    unsigned zz = *(const unsigned*)&Zh[((unsigned)cl << 7) + zoff];
    acc0 = fmaf(xv, bf2f((ushort)(zz & 0xffff)), acc0);
    acc1 = fmaf(xv, bf2f((ushort)(zz >> 16)), acc1);
    sum += xv;
  }
  float inv = (d > 0) ? 1.0f / sum : 0.f;
  unsigned ob = ((unsigned)n << 7) + (unsigned)(o0 << 2) + h;  // o*4+h layout
  out[ob] = acc0 * inv;
  out[ob + 4] = acc1 * inv;
}

extern "C" void kernel_launch(void* const* d_in, const int* in_sizes, int n_in,
                              void* d_out, int out_size, void* d_ws, size_t ws_size,
                              hipStream_t stream) {
  const float* x   = (const float*)d_in[0];
  const int*   row = (const int*)d_in[1];
  const int*   col = (const int*)d_in[2];
  const float* W   = (const float*)d_in[3];
  const float* b   = (const float*)d_in[4];
  const float* a_l = (const float*)d_in[5];
  const float* a_r = (const float*)d_in[6];
  float* out = (float*)d_out;

  const int N = in_sizes[0] / 128;
  const int E = in_sizes[1];
  const int NB = (N + 255) / 256;

  char* w = (char*)d_ws;
  ushort* Zh       = (ushort*)w;             w += (size_t)N * 128 * 2;
  int*   sorted_col= (int*)w;                w += (size_t)E * 4;
  int*   rank      = (int*)w;                w += (size_t)E * 4;
  float* el        = (float*)w;              w += (size_t)N * 4 * 4;
  float* er        = (float*)w;              w += (size_t)N * 4 * 4;
  int*   deg       = (int*)w;                w += (size_t)N * 4;
  int*   base      = (int*)w;                w += (size_t)N * 4;
  int*   bsum      = (int*)w;                w += 512 * 4;

  hipMemsetAsync(deg, 0, (size_t)N * sizeof(int), stream);

  gemm_z<<<(N + 63) / 64, 256, 0, stream>>>(x, W, b, Zh, N);
  node_e<<<(N * 4 + 255) / 256, 256, 0, stream>>>(Zh, a_l, a_r, el, er, N * 4);
  deg_cnt<<<(E + 255) / 256, 256, 0, stream>>>(row, deg, rank, E);
  scan1<<<NB, 256, 0, stream>>>(deg, base, bsum, N);
  scan2<<<1, 512, 0, stream>>>(bsum, NB);
  fill<<<(E + 255) / 256, 256, 0, stream>>>(row, col, rank, base, bsum,
                                            sorted_col, E);
  gather<<<(N + 3) / 4, 256, 0, stream>>>(base, bsum, deg, sorted_col, el, er,
                                          Zh, out, N);
}